// Round 12
// baseline (200.608 us; speedup 1.0000x reference)
//
#include <hip/hip_runtime.h>
#include <hip/hip_fp16.h>

// GCN 2-layer. 2-phase coalesced bucket build + fp16 gather rows (fp32 accumulate)
// + 64-row GEMM blocks (4x less weight re-fetch) + custom zero kernel.
//   zero:    gcur/novf = 0
//   pass1 (grid 768, 1024-edge batches): edges -> 196 dst-buckets, LDS-staged 64B-line flushes
//   pass2: bucket -> per-node ELL (CAP 80, u16) in LDS, coalesced writeout;
//          computes dinv and zp(fp16) = z*dinv (fused prescale)
//   gather1: agg1(f32)[d] = dinv[d]*(zp[d] + sum zp[s])
//   gemm1:   x1 = relu(agg1 @ W1 + b1)            (64 rows/block, 512 thr)
//   gemm2:   h2(fp16) = (x1 @ W2)*dinv[row]       (64 rows/block, 512 thr)
//   gather2: out = relu(dinv[d]*(h2[d] + sum h2[s]) + b2)

#define NBUK 196          // ceil(50000/256)
#define BCAP 16384        // per-bucket slot capacity (payload ~8.2k + per-block line padding)
#define SCAP 32           // LDS staging slots per bucket
#define ECAP 80           // ELL row capacity (deg ~ Poisson(32); P(>80) ~ 1e-17)
#define SENT 0xFFFFFFFFu
#define P1GRID 768

struct half4_t { __half2 lo, hi; };   // 8 B = 4 halves

__global__ void zero_kernel(int* __restrict__ p, int n) {
    int i = blockIdx.x * blockDim.x + threadIdx.x;
    if (i < n) p[i] = 0;
}

__global__ __launch_bounds__(256) void pass1_kernel(
    const int* __restrict__ src, const int* __restrict__ dst,
    unsigned* __restrict__ bucketed, int* __restrict__ gcur,
    unsigned* __restrict__ ovf, int* __restrict__ novf, int E) {
    __shared__ unsigned stage[NBUK * SCAP];
    __shared__ int lcnt[NBUK];
    __shared__ int bbase[NBUK];
    __shared__ unsigned units[512];
    __shared__ int nunits;
    int tid = threadIdx.x;
    for (int i = tid; i < NBUK; i += 256) lcnt[i] = 0;
    if (tid == 0) nunits = 0;
    int per = (E + gridDim.x - 1) / gridDim.x;
    int lo = blockIdx.x * per, hi = min(E, lo + per);
    __syncthreads();
    for (int t0 = lo; t0 < hi; t0 += 1024) {
#pragma unroll
        for (int rep = 0; rep < 4; ++rep) {
            int i = t0 + rep * 256 + tid;
            if (i < hi) {
                int s = src[i], d = dst[i];
                int b = d >> 8;
                unsigned pk = (unsigned)(s & 0xFFFF) | ((unsigned)(d & 0xFF) << 16);
                int pos = atomicAdd(&lcnt[b], 1);
                if (pos < SCAP) {
                    stage[b * SCAP + pos] = pk;
                } else {                           // rare batch burst: spill to global list
                    int op = atomicAdd(novf, 1);
                    if (op < 4096) ovf[op] = pk | ((unsigned)b << 24);
                    atomicSub(&lcnt[b], 1);
                }
            }
        }
        __syncthreads();
        if (tid < NBUK) {                          // enumerate full 64B units
            int c = min(lcnt[tid], SCAP);
            int f = c >> 4;
            if (f > 0) {
                bbase[tid] = atomicAdd(&gcur[tid], f * 16);
                int u0 = atomicAdd(&nunits, f);
                for (int g = 0; g < f; ++g) units[u0 + g] = ((unsigned)tid << 8) | g;
            }
        }
        __syncthreads();
        int nu = nunits;
        for (int u = tid >> 4; u < nu; u += 16) {  // 16 lanes write one 64B line
            unsigned ds = units[u];
            int b = ds >> 8, g = ds & 0xFF;
            int li = tid & 15;
            int idx = bbase[b] + g * 16 + li;
            if (idx < BCAP)
                bucketed[(size_t)b * BCAP + idx] = stage[b * SCAP + g * 16 + li];
        }
        __syncthreads();
        if (tid < NBUK) {                          // compact remainder (<16) to front
            int c = min(lcnt[tid], SCAP);
            int f = (c >> 4) << 4;
            int rem = c - f;
            for (int j = 0; j < rem; ++j) stage[tid * SCAP + j] = stage[tid * SCAP + f + j];
            lcnt[tid] = rem;
        }
        if (tid == 0) nunits = 0;
        __syncthreads();
    }
    // final flush: pad remainder to a full line with sentinels
    if (tid < NBUK) {
        int c = min(lcnt[tid], SCAP);              // <= 15 here
        if (c > 0) {
            for (int j = c; j < 16; ++j) stage[tid * SCAP + j] = SENT;
            bbase[tid] = atomicAdd(&gcur[tid], 16);
            int u0 = atomicAdd(&nunits, 1);
            units[u0] = ((unsigned)tid << 8);
        }
    }
    __syncthreads();
    int nu = nunits;
    for (int u = tid >> 4; u < nu; u += 16) {
        unsigned ds = units[u];
        int b = ds >> 8, g = ds & 0xFF;
        int li = tid & 15;
        int idx = bbase[b] + g * 16 + li;
        if (idx < BCAP)
            bucketed[(size_t)b * BCAP + idx] = stage[b * SCAP + g * 16 + li];
    }
}

// One block per bucket: LDS ELL build + coalesced writeout + dinv + fused fp16 prescale.
__global__ __launch_bounds__(256) void pass2_kernel(
    const unsigned* __restrict__ bucketed, const int* __restrict__ gcur,
    const unsigned* __restrict__ ovf, const int* __restrict__ novf,
    const float* __restrict__ z, unsigned short* __restrict__ ellg,
    int* __restrict__ cntg, float* __restrict__ dinv, half4_t* __restrict__ zp, int N) {
    __shared__ unsigned short ell[256 * ECAP];
    __shared__ int lcnt[256];
    __shared__ float dl[256];
    int b = blockIdx.x, tid = threadIdx.x;
    lcnt[tid] = 0;
    __syncthreads();
    int c = min(gcur[b], BCAP);
    const unsigned* bp = bucketed + (size_t)b * BCAP;
    for (int j = tid; j < c; j += 256) {
        unsigned e = bp[j];
        if (e == SENT) continue;
        int r = (e >> 16) & 0xFF;
        int p = atomicAdd(&lcnt[r], 1);
        if (p < ECAP) ell[r * ECAP + p] = (unsigned short)(e & 0xFFFF);
    }
    int no = min(*novf, 4096);
    for (int j = tid; j < no; j += 256) {          // expected ~0 entries
        unsigned e = ovf[j];
        if ((int)(e >> 24) == b) {
            int r = (e >> 16) & 0xFF;
            int p = atomicAdd(&lcnt[r], 1);
            if (p < ECAP) ell[r * ECAP + p] = (unsigned short)(e & 0xFFFF);
        }
    }
    __syncthreads();
    int node = b * 256 + tid;
    float w = 0.f;
    if (node < N) {
        int deg = lcnt[tid];
        w = rsqrtf((float)(deg + 1));
        dinv[node] = w;
        cntg[node] = min(deg, ECAP);
    }
    dl[tid] = w;
    __syncthreads();
    // coalesced ELL writeout as u32: ECAP/2 = 40 u32 per row
    {
        const int W32 = ECAP / 2;
        unsigned* eg = (unsigned*)(ellg + (size_t)b * 256 * ECAP);
        const unsigned* el = (const unsigned*)ell;
        for (int k = tid; k < 256 * W32; k += 256) eg[k] = el[k];
    }
    // fused prescale: zp[node] = fp16(z[node] * dinv[node])
    for (int k = tid; k < 256 * 16; k += 256) {
        int r = k >> 4, q = k & 15;
        int nd = b * 256 + r;
        if (nd < N) {
            float4 v = reinterpret_cast<const float4*>(z)[nd * 16 + q];
            float ww = dl[r];
            half4_t h;
            h.lo = __floats2half2_rn(v.x * ww, v.y * ww);
            h.hi = __floats2half2_rn(v.z * ww, v.w * ww);
            zp[nd * 16 + q] = h;
        }
    }
}

// One wave per node; 4 lane-groups of 16; each group loads 8B (4 halves) per neighbor row.
// EPI=0: out = (self + sum)*dinv ; EPI=1: out = relu((self+sum)*dinv + bias)
template <int EPI>
__global__ __launch_bounds__(256) void gatherv_kernel(
    const half4_t* __restrict__ rows, const int* __restrict__ cnt,
    const unsigned short* __restrict__ ell, const float* __restrict__ dinv,
    const float* __restrict__ bias, float* __restrict__ outp, int N) {
    int node = (blockIdx.x * 256 + threadIdx.x) >> 6;
    int lane = threadIdx.x & 63;
    if (node >= N) return;
    int g = lane >> 4, li = lane & 15;
    float ax = 0.f, ay = 0.f, az = 0.f, aw = 0.f;
    float bx = 0.f, by = 0.f, bz = 0.f, bw = 0.f;
    int cl = cnt[node];
    size_t base = (size_t)node * ECAP;
    int k = g;
    for (; k + 12 < cl; k += 16) {                 // 4 independent streams in flight
        int s0 = ell[base + k];
        int s1 = ell[base + k + 4];
        int s2 = ell[base + k + 8];
        int s3 = ell[base + k + 12];
        half4_t v0 = rows[s0 * 16 + li];
        half4_t v1 = rows[s1 * 16 + li];
        half4_t v2 = rows[s2 * 16 + li];
        half4_t v3 = rows[s3 * 16 + li];
        float2 f;
        f = __half22float2(v0.lo); ax += f.x; ay += f.y;
        f = __half22float2(v0.hi); az += f.x; aw += f.y;
        f = __half22float2(v1.lo); ax += f.x; ay += f.y;
        f = __half22float2(v1.hi); az += f.x; aw += f.y;
        f = __half22float2(v2.lo); bx += f.x; by += f.y;
        f = __half22float2(v2.hi); bz += f.x; bw += f.y;
        f = __half22float2(v3.lo); bx += f.x; by += f.y;
        f = __half22float2(v3.hi); bz += f.x; bw += f.y;
    }
    for (; k + 4 < cl; k += 8) {
        int s0 = ell[base + k];
        int s1 = ell[base + k + 4];
        half4_t v0 = rows[s0 * 16 + li];
        half4_t v1 = rows[s1 * 16 + li];
        float2 f;
        f = __half22float2(v0.lo); ax += f.x; ay += f.y;
        f = __half22float2(v0.hi); az += f.x; aw += f.y;
        f = __half22float2(v1.lo); ax += f.x; ay += f.y;
        f = __half22float2(v1.hi); az += f.x; aw += f.y;
    }
    if (k < cl) {
        int s = ell[base + k];
        half4_t v = rows[s * 16 + li];
        float2 f;
        f = __half22float2(v.lo); ax += f.x; ay += f.y;
        f = __half22float2(v.hi); az += f.x; aw += f.y;
    }
    ax += bx; ay += by; az += bz; aw += bw;
#pragma unroll
    for (int off = 16; off < 64; off <<= 1) {
        ax += __shfl_xor(ax, off, 64);
        ay += __shfl_xor(ay, off, 64);
        az += __shfl_xor(az, off, 64);
        aw += __shfl_xor(aw, off, 64);
    }
    float w = dinv[node];
    {
        half4_t v = rows[node * 16 + li];
        float2 f;
        f = __half22float2(v.lo); ax += f.x; ay += f.y;
        f = __half22float2(v.hi); az += f.x; aw += f.y;
    }
    float4 o;
    if constexpr (EPI == 1) {
        float4 bv = reinterpret_cast<const float4*>(bias)[li];
        o.x = fmaxf(fmaf(ax, w, bv.x), 0.f);
        o.y = fmaxf(fmaf(ay, w, bv.y), 0.f);
        o.z = fmaxf(fmaf(az, w, bv.z), 0.f);
        o.w = fmaxf(fmaf(aw, w, bv.w), 0.f);
    } else {
        o.x = ax * w; o.y = ay * w; o.z = az * w; o.w = aw * w;
    }
    if (g == 0) reinterpret_cast<float4*>(outp)[node * 16 + li] = o;
}

// x1[N,128] = relu(agg1[N,64] @ W1[64,128] + b1)  — 64 rows/block, 512 threads
__global__ __launch_bounds__(512) void gemm1_kernel(
    const float* __restrict__ agg1, const float* __restrict__ W,
    const float* __restrict__ b1, float* __restrict__ x1, int N) {
    __shared__ float wl[64 * 128];    // 32 KB
    __shared__ float zl[64 * 64];     // 16 KB
    __shared__ float bl[128];
    int tid = threadIdx.x;
    for (int i = tid; i < 64 * 128; i += 512) wl[i] = W[i];
    if (tid < 128) bl[tid] = b1[tid];
    int base = blockIdx.x * 64;
    for (int i = tid; i < 64 * 64; i += 512) {
        int r = i >> 6, c = i & 63;
        int node = base + r;
        zl[i] = (node < N) ? agg1[node * 64 + c] : 0.f;
    }
    __syncthreads();
    int j = tid & 127, rb = tid >> 7;  // rows rb+4k, k<16
    float acc[16];
#pragma unroll
    for (int k = 0; k < 16; ++k) acc[k] = 0.f;
    for (int kk = 0; kk < 64; ++kk) {
        float wv = wl[kk * 128 + j];
#pragma unroll
        for (int k = 0; k < 16; ++k)
            acc[k] = fmaf(zl[(rb + 4 * k) * 64 + kk], wv, acc[k]);
    }
#pragma unroll
    for (int k = 0; k < 16; ++k) {
        int node = base + rb + 4 * k;
        if (node < N) x1[node * 128 + j] = fmaxf(acc[k] + bl[j], 0.f);
    }
}

// h2(fp16)[N,64] = (x1[N,128] @ W2[128,64]) * dinv[row]  — 64 rows/block, 512 threads
__global__ __launch_bounds__(512) void gemm2_kernel(
    const float* __restrict__ x1, const float* __restrict__ dinv,
    const float* __restrict__ W, __half* __restrict__ h2, int N) {
    __shared__ float wl[128 * 64];    // 32 KB
    __shared__ float xl[64 * 128];    // 32 KB
    int tid = threadIdx.x;
    for (int i = tid; i < 128 * 64; i += 512) wl[i] = W[i];
    int base = blockIdx.x * 64;
    for (int i = tid; i < 64 * 128; i += 512) {
        int r = i >> 7, c = i & 127;
        int node = base + r;
        xl[i] = (node < N) ? x1[node * 128 + c] : 0.f;
    }
    __syncthreads();
    int j = tid & 63, rb = tid >> 6;   // rows rb+8k, k<8
    float acc[8];
#pragma unroll
    for (int k = 0; k < 8; ++k) acc[k] = 0.f;
    for (int kk = 0; kk < 128; ++kk) {
        float wv = wl[kk * 64 + j];
#pragma unroll
        for (int k = 0; k < 8; ++k)
            acc[k] = fmaf(xl[(rb + 8 * k) * 128 + kk], wv, acc[k]);
    }
#pragma unroll
    for (int k = 0; k < 8; ++k) {
        int node = base + rb + 8 * k;
        if (node < N) h2[node * 64 + j] = __float2half_rn(acc[k] * dinv[node]);
    }
}

extern "C" void kernel_launch(void* const* d_in, const int* in_sizes, int n_in,
                              void* d_out, int out_size, void* d_ws, size_t ws_size,
                              hipStream_t stream) {
    const float* z  = (const float*)d_in[0];
    const int* edges = (const int*)d_in[1];
    const float* W1 = (const float*)d_in[2];
    const float* b1 = (const float*)d_in[3];
    const float* W2 = (const float*)d_in[4];
    const float* b2 = (const float*)d_in[5];
    float* out = (float*)d_out;

    int N = in_sizes[0] / 64;   // 50000
    int E = in_sizes[1] / 2;    // 1600000
    const int* src = edges;
    const int* dst = edges + E;

    const size_t MB = 1024 * 1024;
    char* ws = (char*)d_ws;
    int*            gcur = (int*)(ws);                       // NBUK ints
    int*            novf = (int*)(ws + 4 * 1024);            // 1 int
    unsigned*       ovf  = (unsigned*)(ws + 8 * 1024);       // 4096 entries
    unsigned short* ellg = (unsigned short*)(ws + 1 * MB);   // 196*256*80 u16 (8.03 MB)
    int*            cntg = (int*)(ws + 10 * MB);             // N ints
    float*          dinv = (float*)(ws + 10 * MB + 512 * 1024);
    half4_t*        zp   = (half4_t*)(ws + 11 * MB);         // N*64 fp16 (6.4 MB)
    float*          agg1 = (float*)(ws + 18 * MB);           // N*64 f32 (12.8 MB)
    float*          x1   = (float*)(ws + 31 * MB);           // N*128 f32 (25.6 MB)
    unsigned*       bucketed = (unsigned*)(ws + 57 * MB);    // 196*16384 u32 (12.8 MB)
    __half*         h2   = (__half*)agg1;                    // agg1 dead after gemm2 (6.4 MB)

    zero_kernel<<<(6145 + 255) / 256, 256, 0, stream>>>(gcur, 6145);  // gcur..novf (24 KB)
    pass1_kernel<<<P1GRID, 256, 0, stream>>>(src, dst, bucketed, gcur, ovf, novf, E);
    pass2_kernel<<<NBUK, 256, 0, stream>>>(bucketed, gcur, ovf, novf, z, ellg, cntg, dinv, zp, N);

    gatherv_kernel<0><<<(N + 3) / 4, 256, 0, stream>>>(zp, cntg, ellg, dinv, nullptr, agg1, N);
    gemm1_kernel<<<(N + 63) / 64, 512, 0, stream>>>(agg1, W1, b1, x1, N);
    gemm2_kernel<<<(N + 63) / 64, 512, 0, stream>>>(x1, dinv, W2, h2, N);
    gatherv_kernel<1><<<(N + 3) / 4, 256, 0, stream>>>((const half4_t*)h2, cntg, ellg, dinv, b2, out, N);
}

// Round 13
// 189.852 us; speedup vs baseline: 1.0567x; 1.0567x over previous
//
#include <hip/hip_runtime.h>
#include <hip/hip_fp16.h>

// GCN 2-layer. 2-phase coalesced bucket build + fp16 gather rows (fp32 accumulate)
// + 16-row GEMM blocks (verified round-10 config) + custom zero kernel.
//   zero:    gcur/novf = 0
//   pass1 (grid 768, 1024-edge batches): edges -> 196 dst-buckets, LDS-staged 64B-line flushes
//   pass2: bucket -> per-node ELL (CAP 80, u16) in LDS, coalesced writeout;
//          computes dinv and zp(fp16) = z*dinv (fused prescale)
//   gather1: agg1(f32)[d] = dinv[d]*(zp[d] + sum zp[s])
//   gemm1:   x1 = relu(agg1 @ W1 + b1)            (16 rows/block, 256 thr)
//   gemm2:   h2(fp16) = (x1 @ W2)*dinv[row]       (16 rows/block, 256 thr)
//   gather2: out = relu(dinv[d]*(h2[d] + sum h2[s]) + b2)

#define NBUK 196          // ceil(50000/256)
#define BCAP 16384        // per-bucket slot capacity (payload ~8.2k + per-block line padding)
#define SCAP 32           // LDS staging slots per bucket
#define ECAP 80           // ELL row capacity (deg ~ Poisson(32); P(>80) ~ 1e-17)
#define SENT 0xFFFFFFFFu
#define P1GRID 768

struct half4_t { __half2 lo, hi; };   // 8 B = 4 halves

__global__ void zero_kernel(int* __restrict__ p, int n) {
    int i = blockIdx.x * blockDim.x + threadIdx.x;
    if (i < n) p[i] = 0;
}

__global__ __launch_bounds__(256) void pass1_kernel(
    const int* __restrict__ src, const int* __restrict__ dst,
    unsigned* __restrict__ bucketed, int* __restrict__ gcur,
    unsigned* __restrict__ ovf, int* __restrict__ novf, int E) {
    __shared__ unsigned stage[NBUK * SCAP];
    __shared__ int lcnt[NBUK];
    __shared__ int bbase[NBUK];
    __shared__ unsigned units[512];
    __shared__ int nunits;
    int tid = threadIdx.x;
    for (int i = tid; i < NBUK; i += 256) lcnt[i] = 0;
    if (tid == 0) nunits = 0;
    int per = (E + gridDim.x - 1) / gridDim.x;
    int lo = blockIdx.x * per, hi = min(E, lo + per);
    __syncthreads();
    for (int t0 = lo; t0 < hi; t0 += 1024) {
#pragma unroll
        for (int rep = 0; rep < 4; ++rep) {
            int i = t0 + rep * 256 + tid;
            if (i < hi) {
                int s = src[i], d = dst[i];
                int b = d >> 8;
                unsigned pk = (unsigned)(s & 0xFFFF) | ((unsigned)(d & 0xFF) << 16);
                int pos = atomicAdd(&lcnt[b], 1);
                if (pos < SCAP) {
                    stage[b * SCAP + pos] = pk;
                } else {                           // rare batch burst: spill to global list
                    int op = atomicAdd(novf, 1);
                    if (op < 4096) ovf[op] = pk | ((unsigned)b << 24);
                    atomicSub(&lcnt[b], 1);
                }
            }
        }
        __syncthreads();
        if (tid < NBUK) {                          // enumerate full 64B units
            int c = min(lcnt[tid], SCAP);
            int f = c >> 4;
            if (f > 0) {
                bbase[tid] = atomicAdd(&gcur[tid], f * 16);
                int u0 = atomicAdd(&nunits, f);
                for (int g = 0; g < f; ++g) units[u0 + g] = ((unsigned)tid << 8) | g;
            }
        }
        __syncthreads();
        int nu = nunits;
        for (int u = tid >> 4; u < nu; u += 16) {  // 16 lanes write one 64B line
            unsigned ds = units[u];
            int b = ds >> 8, g = ds & 0xFF;
            int li = tid & 15;
            int idx = bbase[b] + g * 16 + li;
            if (idx < BCAP)
                bucketed[(size_t)b * BCAP + idx] = stage[b * SCAP + g * 16 + li];
        }
        __syncthreads();
        if (tid < NBUK) {                          // compact remainder (<16) to front
            int c = min(lcnt[tid], SCAP);
            int f = (c >> 4) << 4;
            int rem = c - f;
            for (int j = 0; j < rem; ++j) stage[tid * SCAP + j] = stage[tid * SCAP + f + j];
            lcnt[tid] = rem;
        }
        if (tid == 0) nunits = 0;
        __syncthreads();
    }
    // final flush: pad remainder to a full line with sentinels
    if (tid < NBUK) {
        int c = min(lcnt[tid], SCAP);              // <= 15 here
        if (c > 0) {
            for (int j = c; j < 16; ++j) stage[tid * SCAP + j] = SENT;
            bbase[tid] = atomicAdd(&gcur[tid], 16);
            int u0 = atomicAdd(&nunits, 1);
            units[u0] = ((unsigned)tid << 8);
        }
    }
    __syncthreads();
    int nu = nunits;
    for (int u = tid >> 4; u < nu; u += 16) {
        unsigned ds = units[u];
        int b = ds >> 8, g = ds & 0xFF;
        int li = tid & 15;
        int idx = bbase[b] + g * 16 + li;
        if (idx < BCAP)
            bucketed[(size_t)b * BCAP + idx] = stage[b * SCAP + g * 16 + li];
    }
}

// One block per bucket: LDS ELL build + coalesced writeout + dinv + fused fp16 prescale.
__global__ __launch_bounds__(256) void pass2_kernel(
    const unsigned* __restrict__ bucketed, const int* __restrict__ gcur,
    const unsigned* __restrict__ ovf, const int* __restrict__ novf,
    const float* __restrict__ z, unsigned short* __restrict__ ellg,
    int* __restrict__ cntg, float* __restrict__ dinv, half4_t* __restrict__ zp, int N) {
    __shared__ unsigned short ell[256 * ECAP];
    __shared__ int lcnt[256];
    __shared__ float dl[256];
    int b = blockIdx.x, tid = threadIdx.x;
    lcnt[tid] = 0;
    __syncthreads();
    int c = min(gcur[b], BCAP);
    const unsigned* bp = bucketed + (size_t)b * BCAP;
    for (int j = tid; j < c; j += 256) {
        unsigned e = bp[j];
        if (e == SENT) continue;
        int r = (e >> 16) & 0xFF;
        int p = atomicAdd(&lcnt[r], 1);
        if (p < ECAP) ell[r * ECAP + p] = (unsigned short)(e & 0xFFFF);
    }
    int no = min(*novf, 4096);
    for (int j = tid; j < no; j += 256) {          // expected ~0 entries
        unsigned e = ovf[j];
        if ((int)(e >> 24) == b) {
            int r = (e >> 16) & 0xFF;
            int p = atomicAdd(&lcnt[r], 1);
            if (p < ECAP) ell[r * ECAP + p] = (unsigned short)(e & 0xFFFF);
        }
    }
    __syncthreads();
    int node = b * 256 + tid;
    float w = 0.f;
    if (node < N) {
        int deg = lcnt[tid];
        w = rsqrtf((float)(deg + 1));
        dinv[node] = w;
        cntg[node] = min(deg, ECAP);
    }
    dl[tid] = w;
    __syncthreads();
    // coalesced ELL writeout as u32: ECAP/2 = 40 u32 per row
    {
        const int W32 = ECAP / 2;
        unsigned* eg = (unsigned*)(ellg + (size_t)b * 256 * ECAP);
        const unsigned* el = (const unsigned*)ell;
        for (int k = tid; k < 256 * W32; k += 256) eg[k] = el[k];
    }
    // fused prescale: zp[node] = fp16(z[node] * dinv[node])
    for (int k = tid; k < 256 * 16; k += 256) {
        int r = k >> 4, q = k & 15;
        int nd = b * 256 + r;
        if (nd < N) {
            float4 v = reinterpret_cast<const float4*>(z)[nd * 16 + q];
            float ww = dl[r];
            half4_t h;
            h.lo = __floats2half2_rn(v.x * ww, v.y * ww);
            h.hi = __floats2half2_rn(v.z * ww, v.w * ww);
            zp[nd * 16 + q] = h;
        }
    }
}

// One wave per node; 4 lane-groups of 16; each group loads 8B (4 halves) per neighbor row.
// EPI=0: out = (self + sum)*dinv ; EPI=1: out = relu((self+sum)*dinv + bias)
template <int EPI>
__global__ __launch_bounds__(256) void gatherv_kernel(
    const half4_t* __restrict__ rows, const int* __restrict__ cnt,
    const unsigned short* __restrict__ ell, const float* __restrict__ dinv,
    const float* __restrict__ bias, float* __restrict__ outp, int N) {
    int node = (blockIdx.x * 256 + threadIdx.x) >> 6;
    int lane = threadIdx.x & 63;
    if (node >= N) return;
    int g = lane >> 4, li = lane & 15;
    float ax = 0.f, ay = 0.f, az = 0.f, aw = 0.f;
    float bx = 0.f, by = 0.f, bz = 0.f, bw = 0.f;
    int cl = cnt[node];
    size_t base = (size_t)node * ECAP;
    int k = g;
    for (; k + 12 < cl; k += 16) {                 // 4 independent streams in flight
        int s0 = ell[base + k];
        int s1 = ell[base + k + 4];
        int s2 = ell[base + k + 8];
        int s3 = ell[base + k + 12];
        half4_t v0 = rows[s0 * 16 + li];
        half4_t v1 = rows[s1 * 16 + li];
        half4_t v2 = rows[s2 * 16 + li];
        half4_t v3 = rows[s3 * 16 + li];
        float2 f;
        f = __half22float2(v0.lo); ax += f.x; ay += f.y;
        f = __half22float2(v0.hi); az += f.x; aw += f.y;
        f = __half22float2(v1.lo); ax += f.x; ay += f.y;
        f = __half22float2(v1.hi); az += f.x; aw += f.y;
        f = __half22float2(v2.lo); bx += f.x; by += f.y;
        f = __half22float2(v2.hi); bz += f.x; bw += f.y;
        f = __half22float2(v3.lo); bx += f.x; by += f.y;
        f = __half22float2(v3.hi); bz += f.x; bw += f.y;
    }
    for (; k + 4 < cl; k += 8) {
        int s0 = ell[base + k];
        int s1 = ell[base + k + 4];
        half4_t v0 = rows[s0 * 16 + li];
        half4_t v1 = rows[s1 * 16 + li];
        float2 f;
        f = __half22float2(v0.lo); ax += f.x; ay += f.y;
        f = __half22float2(v0.hi); az += f.x; aw += f.y;
        f = __half22float2(v1.lo); ax += f.x; ay += f.y;
        f = __half22float2(v1.hi); az += f.x; aw += f.y;
    }
    if (k < cl) {
        int s = ell[base + k];
        half4_t v = rows[s * 16 + li];
        float2 f;
        f = __half22float2(v.lo); ax += f.x; ay += f.y;
        f = __half22float2(v.hi); az += f.x; aw += f.y;
    }
    ax += bx; ay += by; az += bz; aw += bw;
#pragma unroll
    for (int off = 16; off < 64; off <<= 1) {
        ax += __shfl_xor(ax, off, 64);
        ay += __shfl_xor(ay, off, 64);
        az += __shfl_xor(az, off, 64);
        aw += __shfl_xor(aw, off, 64);
    }
    float w = dinv[node];
    {
        half4_t v = rows[node * 16 + li];
        float2 f;
        f = __half22float2(v.lo); ax += f.x; ay += f.y;
        f = __half22float2(v.hi); az += f.x; aw += f.y;
    }
    float4 o;
    if constexpr (EPI == 1) {
        float4 bv = reinterpret_cast<const float4*>(bias)[li];
        o.x = fmaxf(fmaf(ax, w, bv.x), 0.f);
        o.y = fmaxf(fmaf(ay, w, bv.y), 0.f);
        o.z = fmaxf(fmaf(az, w, bv.z), 0.f);
        o.w = fmaxf(fmaf(aw, w, bv.w), 0.f);
    } else {
        o.x = ax * w; o.y = ay * w; o.z = az * w; o.w = aw * w;
    }
    if (g == 0) reinterpret_cast<float4*>(outp)[node * 16 + li] = o;
}

// x1[N,128] = relu(agg1[N,64] @ W1[64,128] + b1)  — 16 rows/block, 256 threads
__global__ __launch_bounds__(256) void gemm1_kernel(
    const float* __restrict__ agg1, const float* __restrict__ W,
    const float* __restrict__ b1, float* __restrict__ x1, int N) {
    __shared__ float wl[64 * 128];
    __shared__ float zl[16 * 64];
    __shared__ float bl[128];
    int tid = threadIdx.x;
    for (int i = tid; i < 64 * 128; i += 256) wl[i] = W[i];
    if (tid < 128) bl[tid] = b1[tid];
    int base = blockIdx.x * 16;
    for (int i = tid; i < 16 * 64; i += 256) {
        int r = i >> 6, c = i & 63;
        int node = base + r;
        zl[i] = (node < N) ? agg1[node * 64 + c] : 0.f;
    }
    __syncthreads();
    int j = tid & 127, rb = tid >> 7;
    float acc[8];
#pragma unroll
    for (int k = 0; k < 8; ++k) acc[k] = 0.f;
    for (int kk = 0; kk < 64; ++kk) {
        float wv = wl[kk * 128 + j];
#pragma unroll
        for (int k = 0; k < 8; ++k)
            acc[k] = fmaf(zl[(rb + 2 * k) * 64 + kk], wv, acc[k]);
    }
#pragma unroll
    for (int k = 0; k < 8; ++k) {
        int node = base + rb + 2 * k;
        if (node < N) x1[node * 128 + j] = fmaxf(acc[k] + bl[j], 0.f);
    }
}

// h2(fp16)[N,64] = (x1[N,128] @ W2[128,64]) * dinv[row]  — 16 rows/block, 256 threads
__global__ __launch_bounds__(256) void gemm2_kernel(
    const float* __restrict__ x1, const float* __restrict__ dinv,
    const float* __restrict__ W, __half* __restrict__ h2, int N) {
    __shared__ float wl[128 * 64];
    __shared__ float xl[16 * 128];
    int tid = threadIdx.x;
    for (int i = tid; i < 128 * 64; i += 256) wl[i] = W[i];
    int base = blockIdx.x * 16;
    for (int i = tid; i < 16 * 128; i += 256) {
        int r = i >> 7, c = i & 127;
        int node = base + r;
        xl[i] = (node < N) ? x1[node * 128 + c] : 0.f;
    }
    __syncthreads();
    int j = tid & 63, rb = tid >> 6;
    float acc[4] = {0.f, 0.f, 0.f, 0.f};
    for (int kk = 0; kk < 128; ++kk) {
        float wv = wl[kk * 64 + j];
#pragma unroll
        for (int k = 0; k < 4; ++k)
            acc[k] = fmaf(xl[(rb + 4 * k) * 128 + kk], wv, acc[k]);
    }
#pragma unroll
    for (int k = 0; k < 4; ++k) {
        int node = base + rb + 4 * k;
        if (node < N) h2[node * 64 + j] = __float2half_rn(acc[k] * dinv[node]);
    }
}

extern "C" void kernel_launch(void* const* d_in, const int* in_sizes, int n_in,
                              void* d_out, int out_size, void* d_ws, size_t ws_size,
                              hipStream_t stream) {
    const float* z  = (const float*)d_in[0];
    const int* edges = (const int*)d_in[1];
    const float* W1 = (const float*)d_in[2];
    const float* b1 = (const float*)d_in[3];
    const float* W2 = (const float*)d_in[4];
    const float* b2 = (const float*)d_in[5];
    float* out = (float*)d_out;

    int N = in_sizes[0] / 64;   // 50000
    int E = in_sizes[1] / 2;    // 1600000
    const int* src = edges;
    const int* dst = edges + E;

    const size_t MB = 1024 * 1024;
    char* ws = (char*)d_ws;
    int*            gcur = (int*)(ws);                       // NBUK ints
    int*            novf = (int*)(ws + 4 * 1024);            // 1 int
    unsigned*       ovf  = (unsigned*)(ws + 8 * 1024);       // 4096 entries
    unsigned short* ellg = (unsigned short*)(ws + 1 * MB);   // 196*256*80 u16 (8.03 MB)
    int*            cntg = (int*)(ws + 10 * MB);             // N ints
    float*          dinv = (float*)(ws + 10 * MB + 512 * 1024);
    half4_t*        zp   = (half4_t*)(ws + 11 * MB);         // N*64 fp16 (6.4 MB)
    float*          agg1 = (float*)(ws + 18 * MB);           // N*64 f32 (12.8 MB)
    float*          x1   = (float*)(ws + 31 * MB);           // N*128 f32 (25.6 MB)
    unsigned*       bucketed = (unsigned*)(ws + 57 * MB);    // 196*16384 u32 (12.8 MB)
    __half*         h2   = (__half*)agg1;                    // agg1 dead after gemm2 (6.4 MB)

    zero_kernel<<<(6145 + 255) / 256, 256, 0, stream>>>(gcur, 6145);  // gcur..novf (24 KB)
    pass1_kernel<<<P1GRID, 256, 0, stream>>>(src, dst, bucketed, gcur, ovf, novf, E);
    pass2_kernel<<<NBUK, 256, 0, stream>>>(bucketed, gcur, ovf, novf, z, ellg, cntg, dinv, zp, N);

    gatherv_kernel<0><<<(N + 3) / 4, 256, 0, stream>>>(zp, cntg, ellg, dinv, nullptr, agg1, N);
    gemm1_kernel<<<(N + 15) / 16, 256, 0, stream>>>(agg1, W1, b1, x1, N);
    gemm2_kernel<<<(N + 15) / 16, 256, 0, stream>>>(x1, dinv, W2, h2, N);
    gatherv_kernel<1><<<(N + 3) / 4, 256, 0, stream>>>((const half4_t*)h2, cntg, ellg, dinv, b2, out, N);
}